// Round 4
// baseline (1506.246 us; speedup 1.0000x reference)
//
#include <hip/hip_runtime.h>

#define B_   64
#define N_   2304
#define J_   32
#define L_   16
#define EPS_ 1e-7f
#define NSPL 16      // n-splits per batch-group
#define NSL  144     // n per split (NSPL*NSL == N_)
#define BG   4       // batches per block
#define NBLK 256     // 16 b-groups x 16 splits
#define NTHR 1024
#define NT   18      // tiles per iter (NSL/8)

// d_ws layout:
//   ctr  [256] int   : [0..191] per-(t,b) counters, [192..207] W-split counters (memset 0 each call)
//   Ws_g [N*J*L]     : sum_k W
//   p_g  [64][16][512]: per-(b,split) s-partials
//   u_g  [64][512]   : cumulative v

__global__ void __launch_bounds__(NTHR, 4)
caps_kernel(const float* __restrict__ x, const float* __restrict__ W,
            float* __restrict__ out, float* __restrict__ Ws_g,
            float* __restrict__ p_g, float* __restrict__ u_g,
            int* __restrict__ ctr)
{
    __shared__ float xs_lds[BG * NSL];     // 2.3 KB
    __shared__ float u_lds[BG * 512];      // 8 KB
    __shared__ float sred[NTHR * 16];      // 64 KB
    __shared__ int   own_lds[BG];

    const int tid = threadIdx.x;
    const int bi  = blockIdx.x;
    const int sp  = bi & 15;               // consumed n-split
    const int bg  = bi >> 4;               // batch group
    const int nb  = sp * NSL;
    const int bb  = bg * BG;

    const int nl8 = tid >> 7;              // 0..7   (n within tile)
    const int b4  = (tid >> 5) & 3;        // 0..3   (batch within group)
    const int j   = tid & 31;              // capsule

    // ---- 1. reduce own disjoint W slice (9 n-rows) into Ws_g ----
    {
        const int n0 = bi * 9;
        const float4* W4 = (const float4*)W;
        float4* O4 = (float4*)Ws_g;
        for (int o4 = tid; o4 < 9 * 128; o4 += NTHR) {
            const int nn = o4 >> 7;
            const int r  = o4 & 127;       // j*4 + l4
            const float4* base = W4 + (size_t)(n0 + nn) * 1024 + (r >> 2) * 32 + (r & 3);
            float4 s = make_float4(0.f, 0.f, 0.f, 0.f);
#pragma unroll
            for (int k = 0; k < 8; ++k) {
                float4 t = base[k * 4];
                s.x += t.x; s.y += t.y; s.z += t.z; s.w += t.w;
            }
            O4[(size_t)(n0 + nn) * 128 + r] = s;
        }
    }
    __threadfence();
    __syncthreads();
    if (tid == 0)
        __hip_atomic_fetch_add(&ctr[192 + bg], 1, __ATOMIC_RELEASE, __HIP_MEMORY_SCOPE_AGENT);

    // ---- 2. xs for consumed (b, n) range ----
    for (int q = tid; q < BG * NSL; q += NTHR) {
        const int b4f = q / NSL;
        const int nlf = q - b4f * NSL;
        const float4* p4 = (const float4*)(x + ((size_t)(bb + b4f) * N_ + nb + nlf) * 8);
        float4 a = p4[0], c = p4[1];
        xs_lds[b4f * NSL + nlf] = a.x + a.y + a.z + a.w + c.x + c.y + c.z + c.w;
    }

    // ---- 3. wait for consumed Ws split (16 producer blocks) ----
    if (tid == 0) {
        while (__hip_atomic_load(&ctr[192 + sp], __ATOMIC_ACQUIRE, __HIP_MEMORY_SCOPE_AGENT) < 16)
            __builtin_amdgcn_s_sleep(8);
    }
    __syncthreads();
    __threadfence();   // invalidate caches before reading other blocks' Ws slices

    // ---- 4. routing iterations ----
    for (int t = 0; t < 3; ++t) {
        float4 u4[4];
        if (t > 0) {
#pragma unroll
            for (int d = 0; d < 4; ++d)
                u4[d] = ((const float4*)(u_lds + b4 * 512 + j * 16))[d];
        }
        float4 a0 = make_float4(0.f,0.f,0.f,0.f), a1 = a0, a2 = a0, a3 = a0;

        for (int tile = 0; tile < NT; ++tile) {
            const int nl = tile * 8 + nl8;
            const int n  = nb + nl;
            const float4* wr = (const float4*)Ws_g + (size_t)n * 128 + j * 4;
            float4 w0 = wr[0], w1 = wr[1], w2 = wr[2], w3 = wr[3];
            const float xsv = xs_lds[b4 * NSL + nl];
            float wgt;
            if (t == 0) {
                wgt = xsv * (1.0f / 32.0f);
            } else {
                float lg = w0.x*u4[0].x + w0.y*u4[0].y + w0.z*u4[0].z + w0.w*u4[0].w
                         + w1.x*u4[1].x + w1.y*u4[1].y + w1.z*u4[1].z + w1.w*u4[1].w
                         + w2.x*u4[2].x + w2.y*u4[2].y + w2.z*u4[2].z + w2.w*u4[2].w
                         + w3.x*u4[3].x + w3.y*u4[3].y + w3.z*u4[3].z + w3.w*u4[3].w;
                lg *= xsv;
                float e = __expf(lg);       // |lg| < ~25, no overflow; max-pass unnecessary
                float ss = e;
#pragma unroll
                for (int off = 1; off <= 16; off <<= 1) ss += __shfl_xor(ss, off);
                wgt = (e / ss) * xsv;
            }
            a0.x += wgt*w0.x; a0.y += wgt*w0.y; a0.z += wgt*w0.z; a0.w += wgt*w0.w;
            a1.x += wgt*w1.x; a1.y += wgt*w1.y; a1.z += wgt*w1.z; a1.w += wgt*w1.w;
            a2.x += wgt*w2.x; a2.y += wgt*w2.y; a2.z += wgt*w2.z; a2.w += wgt*w2.w;
            a3.x += wgt*w3.x; a3.y += wgt*w3.y; a3.z += wgt*w3.z; a3.w += wgt*w3.w;
        }

        // ---- block-level reduce over the 8 n-lanes ----
        float* sr = sred + tid * 16;
        ((float4*)sr)[0] = a0; ((float4*)sr)[1] = a1;
        ((float4*)sr)[2] = a2; ((float4*)sr)[3] = a3;
        __syncthreads();
        for (int ov = tid; ov < BG * 512; ov += NTHR) {
            const int ob4 = ov >> 9;
            const int jl  = ov & 511;
            const int oj  = jl >> 4;
            const int ol  = jl & 15;
            float s = 0.f;
#pragma unroll
            for (int nl = 0; nl < 8; ++nl)
                s += sred[(nl * 128 + ob4 * 32 + oj) * 16 + ol];
            p_g[((size_t)(bb + ob4) * 16 + sp) * 512 + jl] = s;
        }
        __threadfence();
        __syncthreads();

        if (tid < BG) {
            int old = __hip_atomic_fetch_add(&ctr[t * 64 + bb + tid], 1,
                                             __ATOMIC_ACQ_REL, __HIP_MEMORY_SCOPE_AGENT);
            own_lds[tid] = (old == NSPL - 1);
        }
        __syncthreads();
        __threadfence();   // owners read other blocks' slots

#pragma unroll
        for (int ob = 0; ob < BG; ++ob) {
            if (own_lds[ob]) {             // uniform across block
                const int b = bb + ob;
                if (tid < 512) {
                    float s = 0.f;
#pragma unroll
                    for (int s2 = 0; s2 < NSPL; ++s2)
                        s += p_g[((size_t)b * 16 + s2) * 512 + tid];
                    float sq = s * s;
#pragma unroll
                    for (int off = 1; off <= 8; off <<= 1) sq += __shfl_xor(sq, off);
                    const float scale = sq / (1.f + sq) / sqrtf(sq + EPS_);
                    const float v = scale * s;
                    if (t == 2) out[(size_t)b * 512 + tid] = v;
                    else        u_g[(size_t)b * 512 + tid] = (t == 0 ? v : u_g[(size_t)b * 512 + tid] + v);
                }
                __threadfence();
                __syncthreads();
                if (t < 2 && tid == 0)
                    __hip_atomic_fetch_add(&ctr[t * 64 + b], 1,
                                           __ATOMIC_RELEASE, __HIP_MEMORY_SCOPE_AGENT);
            }
        }

        if (t < 2) {
            if (tid < BG) {
                while (__hip_atomic_load(&ctr[t * 64 + bb + tid], __ATOMIC_ACQUIRE,
                                         __HIP_MEMORY_SCOPE_AGENT) < NSPL + 1)
                    __builtin_amdgcn_s_sleep(8);
            }
            __syncthreads();
            __threadfence();               // fresh u_g
            for (int q = tid; q < BG * 512; q += NTHR) {
                const int qb4 = q >> 9;
                u_lds[q] = u_g[(size_t)(bb + qb4) * 512 + (q & 511)];
            }
            __syncthreads();
        }
    }
}

extern "C" void kernel_launch(void* const* d_in, const int* in_sizes, int n_in,
                              void* d_out, int out_size, void* d_ws, size_t ws_size,
                              hipStream_t stream) {
    const float* x = (const float*)d_in[0];   // [B, N, 8]
    const float* W = (const float*)d_in[1];   // [N, J, 8, L]
    float* out = (float*)d_out;               // [B, J, L]

    int*   ctr  = (int*)d_ws;                          // 256 ints
    float* Ws_g = (float*)d_ws + 256;                  // N*J*L
    float* p_g  = Ws_g + (size_t)N_ * J_ * L_;         // 64*16*512
    float* u_g  = p_g + (size_t)64 * 16 * 512;         // 64*512

    (void)hipMemsetAsync(ctr, 0, 256 * sizeof(int), stream);

    void* args[] = { (void*)&x, (void*)&W, (void*)&out,
                     (void*)&Ws_g, (void*)&p_g, (void*)&u_g, (void*)&ctr };
    (void)hipLaunchCooperativeKernel((const void*)caps_kernel,
                                     dim3(NBLK), dim3(NTHR), args, 0, stream);
}

// Round 5
// 78.086 us; speedup vs baseline: 19.2896x; 19.2896x over previous
//
#include <hip/hip_runtime.h>

#define B_   64
#define N_   2304
#define J_   32
#define L_   16
#define EPS_ 1e-7f
#define BG   4       // batches per block
#define NSPL 16      // n-splits
#define NSL  144     // n per split
#define NTHR 1024
#define NT   18      // tiles (NSL/8)
#define STR  20      // sred per-slot stride in floats (80 B, 16B-aligned, conflict-avoiding)

// ---- prep: Ws[n][j][l] = sum_k W[n][j][k][l];  xs_g[b][n] = sum_i x[b][n][i] ----
__global__ __launch_bounds__(256) void prep_kernel(const float* __restrict__ x,
                                                   const float* __restrict__ W,
                                                   float* __restrict__ Ws,
                                                   float* __restrict__ xs_g) {
    const int o = blockIdx.x * 256 + threadIdx.x;
    const int NW4 = N_ * J_ * L_ / 4;          // 294912 float4 outputs
    if (o < NW4) {
        const int n = o >> 7, r = o & 127;     // r = j*4 + l4
        const float4* base = (const float4*)W + (size_t)n * 1024 + (r >> 2) * 32 + (r & 3);
        float4 s = make_float4(0.f, 0.f, 0.f, 0.f);
#pragma unroll
        for (int k = 0; k < 8; ++k) {
            float4 t = base[k * 4];
            s.x += t.x; s.y += t.y; s.z += t.z; s.w += t.w;
        }
        ((float4*)Ws)[o] = s;
    } else {
        const int q = o - NW4;                 // 0 .. B*N-1
        if (q < B_ * N_) {
            const float4* p4 = (const float4*)(x + (size_t)q * 8);
            float4 a = p4[0], c = p4[1];
            xs_g[q] = a.x + a.y + a.z + a.w + c.x + c.y + c.z + c.w;
        }
    }
}

// ---- one routing iteration. Block = (bg, sp): 4 batches x 144 n. ----
// T=0: uniform weights. T=1: u=squash(sum pA). T=2: u=squash(sum pA)+squash(sum pB).
template<int T>
__global__ __launch_bounds__(NTHR) void iter_kernel(const float* __restrict__ Ws,
                                                    const float* __restrict__ xs_g,
                                                    const float* __restrict__ pA,
                                                    const float* __restrict__ pB,
                                                    float* __restrict__ pout) {
    __shared__ float xs_lds[BG * NSL];         // 2.3 KB
    __shared__ float u_lds[BG * 544];          // 8.7 KB, [b][j*17+l] padded
    __shared__ float sred[512 * STR];          // 40 KB

    const int tid = threadIdx.x;
    const int sp  = blockIdx.x & 15;
    const int bg  = blockIdx.x >> 4;
    const int bb  = bg * BG;
    const int nb  = sp * NSL;

    if (tid < BG * NSL) {
        const int b4f = tid / NSL, nlf = tid - b4f * NSL;
        xs_lds[tid] = xs_g[(size_t)(bb + b4f) * N_ + nb + nlf];
    }

    if constexpr (T > 0) {
        // redundant squash of previous partials -> u_lds (reads 128-256 KB from L2)
        for (int q = tid; q < BG * 512; q += NTHR) {
            const int ob = q >> 9, jl = q & 511;
            const float* pp = pA + ((size_t)(bb + ob) * NSPL) * 512 + jl;
            float s = 0.f;
#pragma unroll
            for (int s2 = 0; s2 < NSPL; ++s2) s += pp[s2 * 512];
            float sq = s * s;
#pragma unroll
            for (int off = 1; off <= 8; off <<= 1) sq += __shfl_xor(sq, off);
            float u = s * (sq / (1.f + sq) / sqrtf(sq + EPS_));
            if constexpr (T == 2) {
                const float* pq = pB + ((size_t)(bb + ob) * NSPL) * 512 + jl;
                float s1 = 0.f;
#pragma unroll
                for (int s2 = 0; s2 < NSPL; ++s2) s1 += pq[s2 * 512];
                float sq1 = s1 * s1;
#pragma unroll
                for (int off = 1; off <= 8; off <<= 1) sq1 += __shfl_xor(sq1, off);
                u += s1 * (sq1 / (1.f + sq1) / sqrtf(sq1 + EPS_));
            }
            u_lds[ob * 544 + (jl >> 4) * 17 + (jl & 15)] = u;
        }
    }
    __syncthreads();

    const int nl8 = tid >> 7;                  // 0..7 n-lane
    const int b4  = (tid >> 5) & 3;            // batch within group
    const int j   = tid & 31;                  // capsule

    float u4[16];
    if constexpr (T > 0) {
#pragma unroll
        for (int l = 0; l < 16; ++l) u4[l] = u_lds[b4 * 544 + j * 17 + l];  // 17*j: bank-bijective
    }

    float acc[16];
#pragma unroll
    for (int l = 0; l < 16; ++l) acc[l] = 0.f;

    const float* wbase = Ws + (size_t)nb * 512 + j * 16;
    const float* xbase = xs_lds + b4 * NSL;

    for (int tile = 0; tile < NT; ++tile) {
        const int nl = tile * 8 + nl8;
        const float4* wr = (const float4*)(wbase + (size_t)nl * 512);
        float4 w0 = wr[0], w1 = wr[1], w2 = wr[2], w3 = wr[3];
        const float xsv = xbase[nl];
        float wgt;
        if constexpr (T == 0) {
            wgt = xsv * (1.f / 32.f);
        } else {
            float lg = w0.x*u4[0]  + w0.y*u4[1]  + w0.z*u4[2]  + w0.w*u4[3]
                     + w1.x*u4[4]  + w1.y*u4[5]  + w1.z*u4[6]  + w1.w*u4[7]
                     + w2.x*u4[8]  + w2.y*u4[9]  + w2.z*u4[10] + w2.w*u4[11]
                     + w3.x*u4[12] + w3.y*u4[13] + w3.z*u4[14] + w3.w*u4[15];
            lg *= xsv;
            float e = __expf(lg);              // |lg| < ~25: no max-pass needed
            float ss = e;
#pragma unroll
            for (int off = 1; off <= 16; off <<= 1) ss += __shfl_xor(ss, off);
            wgt = (e / ss) * xsv;
        }
        acc[0]  += wgt*w0.x; acc[1]  += wgt*w0.y; acc[2]  += wgt*w0.z; acc[3]  += wgt*w0.w;
        acc[4]  += wgt*w1.x; acc[5]  += wgt*w1.y; acc[6]  += wgt*w1.z; acc[7]  += wgt*w1.w;
        acc[8]  += wgt*w2.x; acc[9]  += wgt*w2.y; acc[10] += wgt*w2.z; acc[11] += wgt*w2.w;
        acc[12] += wgt*w3.x; acc[13] += wgt*w3.y; acc[14] += wgt*w3.z; acc[15] += wgt*w3.w;
    }

    // ---- two-stage n-lane reduction (upper half stores, lower half adds) ----
    if (nl8 >= 4) {
        float* sr = sred + (size_t)(tid - 512) * STR;
        ((float4*)sr)[0] = make_float4(acc[0],  acc[1],  acc[2],  acc[3]);
        ((float4*)sr)[1] = make_float4(acc[4],  acc[5],  acc[6],  acc[7]);
        ((float4*)sr)[2] = make_float4(acc[8],  acc[9],  acc[10], acc[11]);
        ((float4*)sr)[3] = make_float4(acc[12], acc[13], acc[14], acc[15]);
    }
    __syncthreads();
    if (nl8 < 4) {
        float* sr = sred + (size_t)tid * STR;
#pragma unroll
        for (int d = 0; d < 4; ++d) {
            float4 t = ((float4*)sr)[d];
            t.x += acc[d*4+0]; t.y += acc[d*4+1]; t.z += acc[d*4+2]; t.w += acc[d*4+3];
            ((float4*)sr)[d] = t;
        }
    }
    __syncthreads();

    // ---- final reduce over 4 slots, write partials (coalesced) ----
    for (int q = tid; q < BG * 512; q += NTHR) {
        const int ob = q >> 9, jl = q & 511;
        const int oj = jl >> 4, ol = jl & 15;
        float s = 0.f;
#pragma unroll
        for (int nl = 0; nl < 4; ++nl)
            s += sred[(size_t)(nl * 128 + ob * 32 + oj) * STR + ol];
        pout[((size_t)(bb + ob) * NSPL + sp) * 512 + jl] = s;
    }
}

// ---- final squash: out[b][j][l] = squash(sum_sp p2) ----
__global__ __launch_bounds__(512) void final_kernel(const float* __restrict__ p2,
                                                    float* __restrict__ out) {
    const int g = blockIdx.x * 512 + threadIdx.x;   // b*512 + jl
    const int b = g >> 9, jl = g & 511;
    const float* pp = p2 + ((size_t)b * NSPL) * 512 + jl;
    float s = 0.f;
#pragma unroll
    for (int s2 = 0; s2 < NSPL; ++s2) s += pp[s2 * 512];
    float sq = s * s;
#pragma unroll
    for (int off = 1; off <= 8; off <<= 1) sq += __shfl_xor(sq, off);
    out[g] = s * (sq / (1.f + sq) / sqrtf(sq + EPS_));
}

extern "C" void kernel_launch(void* const* d_in, const int* in_sizes, int n_in,
                              void* d_out, int out_size, void* d_ws, size_t ws_size,
                              hipStream_t stream) {
    const float* x = (const float*)d_in[0];   // [B, N, 8]
    const float* W = (const float*)d_in[1];   // [N, J, 8, L]
    float* out = (float*)d_out;               // [B, J, L]

    float* Ws  = (float*)d_ws;                         // N*J*L      = 1179648
    float* xsg = Ws  + (size_t)N_ * J_ * L_;           // B*N        = 147456
    float* p0  = xsg + (size_t)B_ * N_;                // B*NSPL*512 = 524288
    float* p1  = p0  + (size_t)B_ * NSPL * 512;
    float* p2  = p1  + (size_t)B_ * NSPL * 512;        // total ~11.6 MB

    prep_kernel<<<1728, 256, 0, stream>>>(x, W, Ws, xsg);
    iter_kernel<0><<<256, NTHR, 0, stream>>>(Ws, xsg, nullptr, nullptr, p0);
    iter_kernel<1><<<256, NTHR, 0, stream>>>(Ws, xsg, p0, nullptr, p1);
    iter_kernel<2><<<256, NTHR, 0, stream>>>(Ws, xsg, p0, p1, p2);
    final_kernel<<<64, 512, 0, stream>>>(p2, out);
}